// Round 4
// baseline (227.651 us; speedup 1.0000x reference)
//
#include <hip/hip_runtime.h>
#include <hip/hip_bf16.h>

// Round 4: GEMM de-stall.
// - qkv_gemm/out_gemm: double-buffered LDS staging (prefetch k+1 issued before
//   the compute phase -> barrier drain no longer exposes full load latency).
// - XOR chunk swizzle (c ^= (row>>1)&3) on GEMM staging, implemented on the
//   per-lane *global* pointer (global_load_lds LDS addr is lane-fixed), so
//   b128 fragment reads go from 8-way bank aliasing to 2-way (free, m136).
// - attn unchanged from round 3.

typedef __bf16 bf16_t;
typedef __bf16 bf16x4 __attribute__((ext_vector_type(4)));
typedef __bf16 bf16x8 __attribute__((ext_vector_type(8)));
typedef float f32x4 __attribute__((ext_vector_type(4)));

#define AS_GLOBAL __attribute__((address_space(1)))
#define AS_LDS    __attribute__((address_space(3)))

__device__ __forceinline__ void async_load16(const void* g, void* l) {
    __builtin_amdgcn_global_load_lds((AS_GLOBAL void*)(g), (AS_LDS void*)(l), 16, 0, 0);
}

// ---------------- fp32 -> bf16 conversion (x) ----------------
__global__ __launch_bounds__(256) void cvt_f32_bf16(const float* __restrict__ src,
                                                    bf16_t* __restrict__ dst, int n4) {
    int i = blockIdx.x * 256 + threadIdx.x;
    if (i < n4) {
        float4 v = ((const float4*)src)[i];
        bf16x4 o;
        o[0] = (bf16_t)v.x; o[1] = (bf16_t)v.y; o[2] = (bf16_t)v.z; o[3] = (bf16_t)v.w;
        ((bf16x4*)dst)[i] = o;
    }
}

// ---------------- 4x fp32 [K,N] -> bf16 transposed [N,K], fused ----------------
__global__ __launch_bounds__(256) void transpose_cvt4(
    const float* __restrict__ W0, const float* __restrict__ W1,
    const float* __restrict__ W2, const float* __restrict__ W3,
    bf16_t* __restrict__ outbase) {
    __shared__ bf16_t T[64][65];
    int t = threadIdx.x;
    int k0 = blockIdx.x * 64, n0 = blockIdx.y * 64, z = blockIdx.z;
    const float* W = (z == 0) ? W0 : (z == 1) ? W1 : (z == 2) ? W2 : W3;
    bf16_t* WT = outbase + (size_t)z * 1048576;
#pragma unroll
    for (int c = 0; c < 4; c++) {
        int idx = c * 256 + t;
        int row = idx >> 4;
        int col4 = (idx & 15) * 4;
        float4 v = *(const float4*)(W + (k0 + row) * 1024 + n0 + col4);
        T[row][col4 + 0] = (bf16_t)v.x;
        T[row][col4 + 1] = (bf16_t)v.y;
        T[row][col4 + 2] = (bf16_t)v.z;
        T[row][col4 + 3] = (bf16_t)v.w;
    }
    __syncthreads();
#pragma unroll
    for (int c = 0; c < 4; c++) {
        int idx = c * 256 + t;
        int nrow = idx >> 4;
        int kc4 = (idx & 15) * 4;
        bf16x4 o;
        o[0] = T[kc4 + 0][nrow];
        o[1] = T[kc4 + 1][nrow];
        o[2] = T[kc4 + 2][nrow];
        o[3] = T[kc4 + 3][nrow];
        *(bf16x4*)(WT + (n0 + nrow) * 1024 + k0 + kc4) = o;
    }
}

// ---------------- fused QKV GEMM (double-buffered, swizzled) ----------------
// z=0: Q natural [B,H,S,64]
// z=1: K tiled-swizzled: per (b,h): [kt][row=s%64][chunk^(row%8)][d%8]
// z=2: V^T tiled-swizzled: per (b,h): [kt][d][chunk^(d%8)][s%8]
__global__ __launch_bounds__(256) void qkv_gemm(
    const bf16_t* __restrict__ A,
    const bf16_t* __restrict__ WqT, const bf16_t* __restrict__ WkT,
    const bf16_t* __restrict__ WvT,
    bf16_t* __restrict__ Qo, bf16_t* __restrict__ Ko, bf16_t* __restrict__ Vo) {
    const int KD = 1024;
    __shared__ bf16_t As[2][128 * 32];
    __shared__ bf16_t Bs[2][128 * 32];
    int tid = threadIdx.x;
    int wave = tid >> 6, lane = tid & 63;
    int quad = lane >> 4, l16 = lane & 15;
    int wm = wave >> 1, wn = wave & 1;
    int z = blockIdx.z;
    const bf16_t* BT = (z == 0) ? WqT : (z == 1) ? WkT : WvT;
    int m0 = blockIdx.x * 128;
    int n0 = blockIdx.y * 128;

    int r = tid >> 2;
    // chunk swizzle: LDS slot (r, c) holds global chunk c ^ ((r>>1)&3)
    int c8 = (((tid & 3) ^ ((tid >> 3) & 3))) * 8;
    const bf16_t* gA0 = A + (size_t)(m0 + r) * KD + c8;
    const bf16_t* gA1 = A + (size_t)(m0 + 64 + r) * KD + c8;
    const bf16_t* gB0 = BT + (size_t)(n0 + r) * KD + c8;
    const bf16_t* gB1 = BT + (size_t)(n0 + 64 + r) * KD + c8;

    f32x4 acc[4][4];
#pragma unroll
    for (int i = 0; i < 4; i++)
#pragma unroll
        for (int j = 0; j < 4; j++) acc[i][j] = (f32x4){0.f, 0.f, 0.f, 0.f};

    // prologue: stage k=0 into buffer 0
    async_load16(gA0, As[0] + wave * 512);
    async_load16(gA1, As[0] + 2048 + wave * 512);
    async_load16(gB0, Bs[0] + wave * 512);
    async_load16(gB1, Bs[0] + 2048 + wave * 512);
    __syncthreads();

    for (int kk = 0; kk < 32; kk++) {
        int cur = kk & 1;
        if (kk < 31) {  // prefetch next slab into the other buffer
            int k0 = (kk + 1) * 32;
            async_load16(gA0 + k0, As[cur ^ 1] + wave * 512);
            async_load16(gA1 + k0, As[cur ^ 1] + 2048 + wave * 512);
            async_load16(gB0 + k0, Bs[cur ^ 1] + wave * 512);
            async_load16(gB1 + k0, Bs[cur ^ 1] + 2048 + wave * 512);
        }
        bf16x8 af[4], bfr[4];
        int csw = (quad ^ ((l16 >> 1) & 3)) * 8;
#pragma unroll
        for (int mt = 0; mt < 4; mt++)
            af[mt] = *(const bf16x8*)(As[cur] + (wm * 64 + mt * 16 + l16) * 32 + csw);
#pragma unroll
        for (int nt = 0; nt < 4; nt++)
            bfr[nt] = *(const bf16x8*)(Bs[cur] + (wn * 64 + nt * 16 + l16) * 32 + csw);
        if (z == 2) {
#pragma unroll
            for (int mt = 0; mt < 4; mt++)
#pragma unroll
                for (int nt = 0; nt < 4; nt++)
                    acc[mt][nt] = __builtin_amdgcn_mfma_f32_16x16x32_bf16(
                        bfr[nt], af[mt], acc[mt][nt], 0, 0, 0);
        } else {
#pragma unroll
            for (int mt = 0; mt < 4; mt++)
#pragma unroll
                for (int nt = 0; nt < 4; nt++)
                    acc[mt][nt] = __builtin_amdgcn_mfma_f32_16x16x32_bf16(
                        af[mt], bfr[nt], acc[mt][nt], 0, 0, 0);
        }
        __syncthreads();  // all waves done with cur + prefetch drained
    }

    if (z == 0) {
#pragma unroll
        for (int mt = 0; mt < 4; mt++) {
            int mg_base = m0 + wm * 64 + mt * 16 + quad * 4;
#pragma unroll
            for (int nt = 0; nt < 4; nt++) {
                int ng = n0 + wn * 64 + nt * 16 + l16;
                int h = ng >> 6, d = ng & 63;
#pragma unroll
                for (int rr = 0; rr < 4; rr++) {
                    int mg = mg_base + rr;
                    int b = mg >> 11, s = mg & 2047;
                    Qo[(((size_t)(b * 16 + h) * 2048) + s) * 64 + d] =
                        (bf16_t)acc[mt][nt][rr];
                }
            }
        }
    } else if (z == 1) {
#pragma unroll
        for (int mt = 0; mt < 4; mt++) {
            int mg_base = m0 + wm * 64 + mt * 16 + quad * 4;
#pragma unroll
            for (int nt = 0; nt < 4; nt++) {
                int ng = n0 + wn * 64 + nt * 16 + l16;
                int h = ng >> 6, dd = ng & 63;
#pragma unroll
                for (int rr = 0; rr < 4; rr++) {
                    int mg = mg_base + rr;
                    int b = mg >> 11, sl = mg & 2047;
                    int kt = sl >> 6, row = sl & 63;
                    int cc = (dd >> 3) ^ (row & 7);
                    Ko[(size_t)(b * 16 + h) * 131072 + kt * 4096 + row * 64 +
                       cc * 8 + (dd & 7)] = (bf16_t)acc[mt][nt][rr];
                }
            }
        }
    } else {
#pragma unroll
        for (int mt = 0; mt < 4; mt++) {
            int sg = m0 + wm * 64 + mt * 16 + l16;
            int b = sg >> 11, sl = sg & 2047;
            int kt = sl >> 6, srow = sl & 63;
#pragma unroll
            for (int nt = 0; nt < 4; nt++) {
                int dg_base = n0 + wn * 64 + nt * 16 + quad * 4;
#pragma unroll
                for (int rr = 0; rr < 4; rr++) {
                    int dg = dg_base + rr;
                    int h = dg >> 6, dd = dg & 63;
                    int cc = (srow >> 3) ^ (dd & 7);
                    Vo[(size_t)(b * 16 + h) * 131072 + kt * 4096 + dd * 64 +
                       cc * 8 + (srow & 7)] = (bf16_t)acc[mt][nt][rr];
                }
            }
        }
    }
}

// ---------------- flash attention (round 3, unchanged) ----------------
__device__ __forceinline__ float exp_pwrite(f32x4 sc[4], bf16_t* Ps,
                                            int wave, int quad, int l16) {
    float part = 0.f;
    int rowbase = (wave * 16 + l16) * 64;
    int gran = (quad & 1) * 4;
    int chi = quad >> 1;
#pragma unroll
    for (int nt = 0; nt < 4; nt++) {
        f32x4 p;
#pragma unroll
        for (int rr = 0; rr < 4; rr++) {
            p[rr] = __builtin_amdgcn_exp2f(sc[nt][rr]);
            part += p[rr];
        }
        bf16x4 pb;
#pragma unroll
        for (int rr = 0; rr < 4; rr++) pb[rr] = (bf16_t)p[rr];
        int cc = (nt * 2 + chi) ^ (l16 & 7);
        *(bf16x4*)(Ps + rowbase + cc * 8 + gran) = pb;
    }
    part += __shfl_xor(part, 16);
    part += __shfl_xor(part, 32);
    return part;
}

__global__ __launch_bounds__(256) void attn(
    const bf16_t* __restrict__ Q, const bf16_t* __restrict__ Kt,
    const bf16_t* __restrict__ Vt, bf16_t* __restrict__ ctx) {
    const int S = 2048;
    __shared__ bf16_t Ks[2][4096];
    __shared__ bf16_t Vs[2][4096];
    __shared__ bf16_t Psa[4096];
    __shared__ bf16_t Psb[4096];
    int tid = threadIdx.x, wave = tid >> 6, lane = tid & 63;
    int quad = lane >> 4, l16 = lane & 15;

    int f = blockIdx.x + 16 * (blockIdx.y + 16 * blockIdx.z);
    int xcd = f & 7, slot = f >> 3;
    int qa = (xcd & 1) * 8 + (slot & 7);
    int bh = (xcd >> 1) + 4 * (slot >> 3);
    int qb = 31 - qa;
    int h = bh & 15, b = bh >> 4;

    const bf16_t* Qbh = Q + (size_t)bh * S * 64;
    const bf16_t* Kbh = Kt + (size_t)bh * 131072;
    const bf16_t* Vbh = Vt + (size_t)bh * 131072;

    const float qs = 0.125f * 1.44269504f;
    bf16x8 aQa[2], aQb[2];
    {
        const bf16_t* ra = Qbh + (size_t)(qa * 64 + wave * 16 + l16) * 64;
        const bf16_t* rb = Qbh + (size_t)(qb * 64 + wave * 16 + l16) * 64;
#pragma unroll
        for (int ks = 0; ks < 2; ks++) {
            bf16x8 ta = *(const bf16x8*)(ra + ks * 32 + quad * 8);
            bf16x8 tb = *(const bf16x8*)(rb + ks * 32 + quad * 8);
#pragma unroll
            for (int j = 0; j < 8; j++) {
                ta[j] = (bf16_t)((float)ta[j] * qs);
                tb[j] = (bf16_t)((float)tb[j] * qs);
            }
            aQa[ks] = ta;
            aQb[ks] = tb;
        }
    }

    float La = 0.f, Lb = 0.f;
    f32x4 Oa[4], Ob[4];
#pragma unroll
    for (int i = 0; i < 4; i++) {
        Oa[i] = (f32x4){0.f, 0.f, 0.f, 0.f};
        Ob[i] = (f32x4){0.f, 0.f, 0.f, 0.f};
    }

    {
        const bf16_t* kg = Kbh + tid * 8;
        const bf16_t* vg = Vbh + tid * 8;
        async_load16(kg, Ks[0] + wave * 512);
        async_load16(kg + 2048, Ks[0] + 2048 + wave * 512);
        async_load16(vg, Vs[0] + wave * 512);
        async_load16(vg + 2048, Vs[0] + 2048 + wave * 512);
    }
    __syncthreads();

    for (int kt = 0; kt <= qb; kt++) {
        int cur = kt & 1;
        if (kt < qb) {
            const bf16_t* kg = Kbh + (kt + 1) * 4096 + tid * 8;
            const bf16_t* vg = Vbh + (kt + 1) * 4096 + tid * 8;
            async_load16(kg, Ks[cur ^ 1] + wave * 512);
            async_load16(kg + 2048, Ks[cur ^ 1] + 2048 + wave * 512);
            async_load16(vg, Vs[cur ^ 1] + wave * 512);
            async_load16(vg + 2048, Vs[cur ^ 1] + 2048 + wave * 512);
        }
        bool dual = (kt <= qa);

        bf16x8 kf[4][2], vf[4][2];
#pragma unroll
        for (int nt = 0; nt < 4; nt++) {
            const bf16_t* krow = Ks[cur] + (nt * 16 + l16) * 64;
            const bf16_t* vrow = Vs[cur] + (nt * 16 + l16) * 64;
#pragma unroll
            for (int ks = 0; ks < 2; ks++) {
                int csw = ((ks * 4 + quad) ^ (l16 & 7)) * 8;
                kf[nt][ks] = *(const bf16x8*)(krow + csw);
                vf[nt][ks] = *(const bf16x8*)(vrow + csw);
            }
        }

        f32x4 sb[4], sa[4];
#pragma unroll
        for (int nt = 0; nt < 4; nt++) {
            f32x4 s = (f32x4){0.f, 0.f, 0.f, 0.f};
            s = __builtin_amdgcn_mfma_f32_16x16x32_bf16(kf[nt][0], aQb[0], s, 0, 0, 0);
            s = __builtin_amdgcn_mfma_f32_16x16x32_bf16(kf[nt][1], aQb[1], s, 0, 0, 0);
            sb[nt] = s;
            if (dual) {
                f32x4 t = (f32x4){0.f, 0.f, 0.f, 0.f};
                t = __builtin_amdgcn_mfma_f32_16x16x32_bf16(kf[nt][0], aQa[0], t, 0, 0, 0);
                t = __builtin_amdgcn_mfma_f32_16x16x32_bf16(kf[nt][1], aQa[1], t, 0, 0, 0);
                sa[nt] = t;
            }
        }
        if (kt == qb) {
            int qg = qb * 64 + wave * 16 + l16;
#pragma unroll
            for (int nt = 0; nt < 4; nt++)
#pragma unroll
                for (int rr = 0; rr < 4; rr++)
                    if (kt * 64 + nt * 16 + quad * 4 + rr > qg) sb[nt][rr] = -1e30f;
        }
        Lb += exp_pwrite(sb, Psb, wave, quad, l16);
        if (dual) {
            if (kt == qa) {
                int qg = qa * 64 + wave * 16 + l16;
#pragma unroll
                for (int nt = 0; nt < 4; nt++)
#pragma unroll
                    for (int rr = 0; rr < 4; rr++)
                        if (kt * 64 + nt * 16 + quad * 4 + rr > qg) sa[nt][rr] = -1e30f;
            }
            La += exp_pwrite(sa, Psa, wave, quad, l16);
        }

#pragma unroll
        for (int ks = 0; ks < 2; ks++) {
            int csw = ((ks * 4 + quad) ^ (l16 & 7)) * 8;
            bf16x8 aPb = *(const bf16x8*)(Psb + (wave * 16 + l16) * 64 + csw);
            bf16x8 aPa;
            if (dual) aPa = *(const bf16x8*)(Psa + (wave * 16 + l16) * 64 + csw);
#pragma unroll
            for (int nt = 0; nt < 4; nt++) {
                Ob[nt] = __builtin_amdgcn_mfma_f32_16x16x32_bf16(aPb, vf[nt][ks],
                                                                 Ob[nt], 0, 0, 0);
                if (dual)
                    Oa[nt] = __builtin_amdgcn_mfma_f32_16x16x32_bf16(aPa, vf[nt][ks],
                                                                     Oa[nt], 0, 0, 0);
            }
        }
        __syncthreads();
    }

    float ila[4], ilb[4];
#pragma unroll
    for (int rr = 0; rr < 4; rr++) {
        ila[rr] = 1.f / __shfl(La, quad * 4 + rr);
        ilb[rr] = 1.f / __shfl(Lb, quad * 4 + rr);
    }
#pragma unroll
    for (int nt = 0; nt < 4; nt++) {
#pragma unroll
        for (int rr = 0; rr < 4; rr++) {
            int qoff = wave * 16 + quad * 4 + rr;
            int col = h * 64 + nt * 16 + l16;
            ctx[(size_t)(b * 2048 + qa * 64 + qoff) * 1024 + col] =
                (bf16_t)(Oa[nt][rr] * ila[rr]);
            ctx[(size_t)(b * 2048 + qb * 64 + qoff) * 1024 + col] =
                (bf16_t)(Ob[nt][rr] * ilb[rr]);
        }
    }
}

// ---------------- out projection (double-buffered, swizzled) ----------------
__global__ __launch_bounds__(256) void out_gemm(
    const bf16_t* __restrict__ A, const bf16_t* __restrict__ BT,
    const float* __restrict__ bias, float* __restrict__ Cout) {
    const int KD = 1024;
    __shared__ bf16_t As[2][128 * 32];
    __shared__ bf16_t Bs[2][128 * 32];
    int tid = threadIdx.x;
    int wave = tid >> 6, lane = tid & 63;
    int quad = lane >> 4, l16 = lane & 15;
    int wm = wave >> 1, wn = wave & 1;
    int m0 = blockIdx.x * 128;
    int n0 = blockIdx.y * 128;

    int r = tid >> 2;
    int c8 = (((tid & 3) ^ ((tid >> 3) & 3))) * 8;
    const bf16_t* gA0 = A + (size_t)(m0 + r) * KD + c8;
    const bf16_t* gA1 = A + (size_t)(m0 + 64 + r) * KD + c8;
    const bf16_t* gB0 = BT + (size_t)(n0 + r) * KD + c8;
    const bf16_t* gB1 = BT + (size_t)(n0 + 64 + r) * KD + c8;

    f32x4 acc[4][4];
#pragma unroll
    for (int i = 0; i < 4; i++)
#pragma unroll
        for (int j = 0; j < 4; j++) acc[i][j] = (f32x4){0.f, 0.f, 0.f, 0.f};

    async_load16(gA0, As[0] + wave * 512);
    async_load16(gA1, As[0] + 2048 + wave * 512);
    async_load16(gB0, Bs[0] + wave * 512);
    async_load16(gB1, Bs[0] + 2048 + wave * 512);
    __syncthreads();

    for (int kk = 0; kk < 32; kk++) {
        int cur = kk & 1;
        if (kk < 31) {
            int k0 = (kk + 1) * 32;
            async_load16(gA0 + k0, As[cur ^ 1] + wave * 512);
            async_load16(gA1 + k0, As[cur ^ 1] + 2048 + wave * 512);
            async_load16(gB0 + k0, Bs[cur ^ 1] + wave * 512);
            async_load16(gB1 + k0, Bs[cur ^ 1] + 2048 + wave * 512);
        }
        bf16x8 af[4], bfr[4];
        int csw = (quad ^ ((l16 >> 1) & 3)) * 8;
#pragma unroll
        for (int mt = 0; mt < 4; mt++)
            af[mt] = *(const bf16x8*)(As[cur] + (wm * 64 + mt * 16 + l16) * 32 + csw);
#pragma unroll
        for (int nt = 0; nt < 4; nt++)
            bfr[nt] = *(const bf16x8*)(Bs[cur] + (wn * 64 + nt * 16 + l16) * 32 + csw);
#pragma unroll
        for (int mt = 0; mt < 4; mt++)
#pragma unroll
            for (int nt = 0; nt < 4; nt++)
                acc[mt][nt] = __builtin_amdgcn_mfma_f32_16x16x32_bf16(af[mt], bfr[nt],
                                                                      acc[mt][nt], 0, 0, 0);
        __syncthreads();
    }

#pragma unroll
    for (int mt = 0; mt < 4; mt++) {
        int mg_base = m0 + wm * 64 + mt * 16 + quad * 4;
#pragma unroll
        for (int nt = 0; nt < 4; nt++) {
            int ng = n0 + wn * 64 + nt * 16 + l16;
            float bv = bias[ng];
#pragma unroll
            for (int rr = 0; rr < 4; rr++) {
                int mg = mg_base + rr;
                Cout[(size_t)mg * 1024 + ng] = acc[mt][nt][rr] + bv;
            }
        }
    }
}

extern "C" void kernel_launch(void* const* d_in, const int* in_sizes, int n_in,
                              void* d_out, int out_size, void* d_ws, size_t ws_size,
                              hipStream_t stream) {
    const float* x  = (const float*)d_in[0];
    const float* Wq = (const float*)d_in[1];
    const float* Wk = (const float*)d_in[2];
    const float* Wv = (const float*)d_in[3];
    const float* Wo = (const float*)d_in[4];
    const float* bo = (const float*)d_in[5];
    float* out = (float*)d_out;
    char* ws = (char*)d_ws;

    bf16_t* xb   = (bf16_t*)(ws);                       // 8 MB
    bf16_t* WTs  = (bf16_t*)(ws + (8u << 20));          // 4x2 MB
    bf16_t* WqT  = WTs;
    bf16_t* WkT  = WTs + 1048576;
    bf16_t* WvT  = WTs + 2097152;
    bf16_t* WoT  = WTs + 3145728;
    bf16_t* Qb   = (bf16_t*)(ws + (16u << 20));         // 8 MB natural
    bf16_t* Kb   = (bf16_t*)(ws + (24u << 20));         // 8 MB tiled-swizzled
    bf16_t* Vb   = (bf16_t*)(ws + (32u << 20));         // 8 MB tiled-swizzled V^T
    bf16_t* ctxb = (bf16_t*)(ws + (40u << 20));         // 8 MB

    cvt_f32_bf16<<<4096, 256, 0, stream>>>(x, xb, (4096 * 1024) / 4);
    transpose_cvt4<<<dim3(16, 16, 4), 256, 0, stream>>>(Wq, Wk, Wv, Wo, WTs);
    qkv_gemm<<<dim3(32, 8, 3), 256, 0, stream>>>(xb, WqT, WkT, WvT, Qb, Kb, Vb);
    attn<<<dim3(16, 16, 2), 256, 0, stream>>>(Qb, Kb, Vb, ctxb);
    out_gemm<<<dim3(32, 8), 256, 0, stream>>>(ctxb, WoT, bo, out);
}

// Round 5
// 218.167 us; speedup vs baseline: 1.0435x; 1.0435x over previous
//
#include <hip/hip_runtime.h>
#include <hip/hip_bf16.h>

// Round 5: occupancy round.
// - attn: UNPAIRED q-tiles -> 1024 blocks (4/CU, 16 waves/CU vs 2/CU before).
//   Balanced mapping: co-resident blocks (f, f+256, f+512, f+768 land on the
//   same CU) get qt = {i, 31-i, i, 31-i} -> per-CU work constant.
// - out_gemm: 64x128 tiles -> 512 blocks (2/CU, 8 waves/CU vs 1 block/CU).
// - qkv_gemm / cvt / transpose unchanged from round 4.

typedef __bf16 bf16_t;
typedef __bf16 bf16x4 __attribute__((ext_vector_type(4)));
typedef __bf16 bf16x8 __attribute__((ext_vector_type(8)));
typedef float f32x4 __attribute__((ext_vector_type(4)));

#define AS_GLOBAL __attribute__((address_space(1)))
#define AS_LDS    __attribute__((address_space(3)))

__device__ __forceinline__ void async_load16(const void* g, void* l) {
    __builtin_amdgcn_global_load_lds((AS_GLOBAL void*)(g), (AS_LDS void*)(l), 16, 0, 0);
}

// ---------------- fp32 -> bf16 conversion (x) ----------------
__global__ __launch_bounds__(256) void cvt_f32_bf16(const float* __restrict__ src,
                                                    bf16_t* __restrict__ dst, int n4) {
    int i = blockIdx.x * 256 + threadIdx.x;
    if (i < n4) {
        float4 v = ((const float4*)src)[i];
        bf16x4 o;
        o[0] = (bf16_t)v.x; o[1] = (bf16_t)v.y; o[2] = (bf16_t)v.z; o[3] = (bf16_t)v.w;
        ((bf16x4*)dst)[i] = o;
    }
}

// ---------------- 4x fp32 [K,N] -> bf16 transposed [N,K], fused ----------------
__global__ __launch_bounds__(256) void transpose_cvt4(
    const float* __restrict__ W0, const float* __restrict__ W1,
    const float* __restrict__ W2, const float* __restrict__ W3,
    bf16_t* __restrict__ outbase) {
    __shared__ bf16_t T[64][65];
    int t = threadIdx.x;
    int k0 = blockIdx.x * 64, n0 = blockIdx.y * 64, z = blockIdx.z;
    const float* W = (z == 0) ? W0 : (z == 1) ? W1 : (z == 2) ? W2 : W3;
    bf16_t* WT = outbase + (size_t)z * 1048576;
#pragma unroll
    for (int c = 0; c < 4; c++) {
        int idx = c * 256 + t;
        int row = idx >> 4;
        int col4 = (idx & 15) * 4;
        float4 v = *(const float4*)(W + (k0 + row) * 1024 + n0 + col4);
        T[row][col4 + 0] = (bf16_t)v.x;
        T[row][col4 + 1] = (bf16_t)v.y;
        T[row][col4 + 2] = (bf16_t)v.z;
        T[row][col4 + 3] = (bf16_t)v.w;
    }
    __syncthreads();
#pragma unroll
    for (int c = 0; c < 4; c++) {
        int idx = c * 256 + t;
        int nrow = idx >> 4;
        int kc4 = (idx & 15) * 4;
        bf16x4 o;
        o[0] = T[kc4 + 0][nrow];
        o[1] = T[kc4 + 1][nrow];
        o[2] = T[kc4 + 2][nrow];
        o[3] = T[kc4 + 3][nrow];
        *(bf16x4*)(WT + (n0 + nrow) * 1024 + k0 + kc4) = o;
    }
}

// ---------------- fused QKV GEMM (round 4, unchanged) ----------------
__global__ __launch_bounds__(256) void qkv_gemm(
    const bf16_t* __restrict__ A,
    const bf16_t* __restrict__ WqT, const bf16_t* __restrict__ WkT,
    const bf16_t* __restrict__ WvT,
    bf16_t* __restrict__ Qo, bf16_t* __restrict__ Ko, bf16_t* __restrict__ Vo) {
    const int KD = 1024;
    __shared__ bf16_t As[2][128 * 32];
    __shared__ bf16_t Bs[2][128 * 32];
    int tid = threadIdx.x;
    int wave = tid >> 6, lane = tid & 63;
    int quad = lane >> 4, l16 = lane & 15;
    int wm = wave >> 1, wn = wave & 1;
    int z = blockIdx.z;
    const bf16_t* BT = (z == 0) ? WqT : (z == 1) ? WkT : WvT;
    int m0 = blockIdx.x * 128;
    int n0 = blockIdx.y * 128;

    int r = tid >> 2;
    int c8 = (((tid & 3) ^ ((tid >> 3) & 3))) * 8;
    const bf16_t* gA0 = A + (size_t)(m0 + r) * KD + c8;
    const bf16_t* gA1 = A + (size_t)(m0 + 64 + r) * KD + c8;
    const bf16_t* gB0 = BT + (size_t)(n0 + r) * KD + c8;
    const bf16_t* gB1 = BT + (size_t)(n0 + 64 + r) * KD + c8;

    f32x4 acc[4][4];
#pragma unroll
    for (int i = 0; i < 4; i++)
#pragma unroll
        for (int j = 0; j < 4; j++) acc[i][j] = (f32x4){0.f, 0.f, 0.f, 0.f};

    async_load16(gA0, As[0] + wave * 512);
    async_load16(gA1, As[0] + 2048 + wave * 512);
    async_load16(gB0, Bs[0] + wave * 512);
    async_load16(gB1, Bs[0] + 2048 + wave * 512);
    __syncthreads();

    for (int kk = 0; kk < 32; kk++) {
        int cur = kk & 1;
        if (kk < 31) {
            int k0 = (kk + 1) * 32;
            async_load16(gA0 + k0, As[cur ^ 1] + wave * 512);
            async_load16(gA1 + k0, As[cur ^ 1] + 2048 + wave * 512);
            async_load16(gB0 + k0, Bs[cur ^ 1] + wave * 512);
            async_load16(gB1 + k0, Bs[cur ^ 1] + 2048 + wave * 512);
        }
        bf16x8 af[4], bfr[4];
        int csw = (quad ^ ((l16 >> 1) & 3)) * 8;
#pragma unroll
        for (int mt = 0; mt < 4; mt++)
            af[mt] = *(const bf16x8*)(As[cur] + (wm * 64 + mt * 16 + l16) * 32 + csw);
#pragma unroll
        for (int nt = 0; nt < 4; nt++)
            bfr[nt] = *(const bf16x8*)(Bs[cur] + (wn * 64 + nt * 16 + l16) * 32 + csw);
        if (z == 2) {
#pragma unroll
            for (int mt = 0; mt < 4; mt++)
#pragma unroll
                for (int nt = 0; nt < 4; nt++)
                    acc[mt][nt] = __builtin_amdgcn_mfma_f32_16x16x32_bf16(
                        bfr[nt], af[mt], acc[mt][nt], 0, 0, 0);
        } else {
#pragma unroll
            for (int mt = 0; mt < 4; mt++)
#pragma unroll
                for (int nt = 0; nt < 4; nt++)
                    acc[mt][nt] = __builtin_amdgcn_mfma_f32_16x16x32_bf16(
                        af[mt], bfr[nt], acc[mt][nt], 0, 0, 0);
        }
        __syncthreads();
    }

    if (z == 0) {
#pragma unroll
        for (int mt = 0; mt < 4; mt++) {
            int mg_base = m0 + wm * 64 + mt * 16 + quad * 4;
#pragma unroll
            for (int nt = 0; nt < 4; nt++) {
                int ng = n0 + wn * 64 + nt * 16 + l16;
                int h = ng >> 6, d = ng & 63;
#pragma unroll
                for (int rr = 0; rr < 4; rr++) {
                    int mg = mg_base + rr;
                    int b = mg >> 11, s = mg & 2047;
                    Qo[(((size_t)(b * 16 + h) * 2048) + s) * 64 + d] =
                        (bf16_t)acc[mt][nt][rr];
                }
            }
        }
    } else if (z == 1) {
#pragma unroll
        for (int mt = 0; mt < 4; mt++) {
            int mg_base = m0 + wm * 64 + mt * 16 + quad * 4;
#pragma unroll
            for (int nt = 0; nt < 4; nt++) {
                int ng = n0 + wn * 64 + nt * 16 + l16;
                int h = ng >> 6, dd = ng & 63;
#pragma unroll
                for (int rr = 0; rr < 4; rr++) {
                    int mg = mg_base + rr;
                    int b = mg >> 11, sl = mg & 2047;
                    int kt = sl >> 6, row = sl & 63;
                    int cc = (dd >> 3) ^ (row & 7);
                    Ko[(size_t)(b * 16 + h) * 131072 + kt * 4096 + row * 64 +
                       cc * 8 + (dd & 7)] = (bf16_t)acc[mt][nt][rr];
                }
            }
        }
    } else {
#pragma unroll
        for (int mt = 0; mt < 4; mt++) {
            int sg = m0 + wm * 64 + mt * 16 + l16;
            int b = sg >> 11, sl = sg & 2047;
            int kt = sl >> 6, srow = sl & 63;
#pragma unroll
            for (int nt = 0; nt < 4; nt++) {
                int dg_base = n0 + wn * 64 + nt * 16 + quad * 4;
#pragma unroll
                for (int rr = 0; rr < 4; rr++) {
                    int dg = dg_base + rr;
                    int h = dg >> 6, dd = dg & 63;
                    int cc = (srow >> 3) ^ (dd & 7);
                    Vo[(size_t)(b * 16 + h) * 131072 + kt * 4096 + dd * 64 +
                       cc * 8 + (srow & 7)] = (bf16_t)acc[mt][nt][rr];
                }
            }
        }
    }
}

// ---------------- flash attention v4: unpaired, 4 blocks/CU ----------------
__device__ __forceinline__ float exp_pwrite(f32x4 sc[4], bf16_t* Ps,
                                            int wave, int quad, int l16) {
    float part = 0.f;
    int rowbase = (wave * 16 + l16) * 64;
    int gran = (quad & 1) * 4;
    int chi = quad >> 1;
#pragma unroll
    for (int nt = 0; nt < 4; nt++) {
        f32x4 p;
#pragma unroll
        for (int rr = 0; rr < 4; rr++) {
            p[rr] = __builtin_amdgcn_exp2f(sc[nt][rr]);
            part += p[rr];
        }
        bf16x4 pb;
#pragma unroll
        for (int rr = 0; rr < 4; rr++) pb[rr] = (bf16_t)p[rr];
        int cc = (nt * 2 + chi) ^ (l16 & 7);
        *(bf16x4*)(Ps + rowbase + cc * 8 + gran) = pb;
    }
    part += __shfl_xor(part, 16);
    part += __shfl_xor(part, 32);
    return part;
}

// grid: 1024 blocks (dim3(32,32)). f = x + 32*y; g=f>>8, s=f&255.
// qt = (g&1)? 31-(s&31) : (s&31);  bh = (s>>5) + 8*g.
// Co-resident CU set {f, f+256, f+512, f+768} -> qt {i,31-i,i,31-i}: balanced.
__global__ __launch_bounds__(256) void attn(
    const bf16_t* __restrict__ Q, const bf16_t* __restrict__ Kt,
    const bf16_t* __restrict__ Vt, bf16_t* __restrict__ ctx) {
    const int S = 2048;
    __shared__ bf16_t Ks[2][4096];
    __shared__ bf16_t Vs[2][4096];
    __shared__ bf16_t Ps[4096];
    int tid = threadIdx.x, wave = tid >> 6, lane = tid & 63;
    int quad = lane >> 4, l16 = lane & 15;

    int f = blockIdx.x + 32 * blockIdx.y;
    int g = f >> 8, s = f & 255;
    int qt = (g & 1) ? (31 - (s & 31)) : (s & 31);
    int bh = (s >> 5) + 8 * g;
    int h = bh & 15, b = bh >> 4;

    const bf16_t* Qbh = Q + (size_t)bh * S * 64;
    const bf16_t* Kbh = Kt + (size_t)bh * 131072;
    const bf16_t* Vbh = Vt + (size_t)bh * 131072;

    const float qs = 0.125f * 1.44269504f;
    bf16x8 aQ[2];
    {
        const bf16_t* rq = Qbh + (size_t)(qt * 64 + wave * 16 + l16) * 64;
#pragma unroll
        for (int ks = 0; ks < 2; ks++) {
            bf16x8 t = *(const bf16x8*)(rq + ks * 32 + quad * 8);
#pragma unroll
            for (int j = 0; j < 8; j++) t[j] = (bf16_t)((float)t[j] * qs);
            aQ[ks] = t;
        }
    }

    float L = 0.f;
    f32x4 O[4];
#pragma unroll
    for (int i = 0; i < 4; i++) O[i] = (f32x4){0.f, 0.f, 0.f, 0.f};

    {
        const bf16_t* kg = Kbh + tid * 8;
        const bf16_t* vg = Vbh + tid * 8;
        async_load16(kg, Ks[0] + wave * 512);
        async_load16(kg + 2048, Ks[0] + 2048 + wave * 512);
        async_load16(vg, Vs[0] + wave * 512);
        async_load16(vg + 2048, Vs[0] + 2048 + wave * 512);
    }
    __syncthreads();

    for (int kt = 0; kt <= qt; kt++) {
        int cur = kt & 1;
        if (kt < qt) {
            const bf16_t* kg = Kbh + (kt + 1) * 4096 + tid * 8;
            const bf16_t* vg = Vbh + (kt + 1) * 4096 + tid * 8;
            async_load16(kg, Ks[cur ^ 1] + wave * 512);
            async_load16(kg + 2048, Ks[cur ^ 1] + 2048 + wave * 512);
            async_load16(vg, Vs[cur ^ 1] + wave * 512);
            async_load16(vg + 2048, Vs[cur ^ 1] + 2048 + wave * 512);
        }

        bf16x8 kf[4][2], vf[4][2];
#pragma unroll
        for (int nt = 0; nt < 4; nt++) {
            const bf16_t* krow = Ks[cur] + (nt * 16 + l16) * 64;
            const bf16_t* vrow = Vs[cur] + (nt * 16 + l16) * 64;
#pragma unroll
            for (int ks = 0; ks < 2; ks++) {
                int csw = ((ks * 4 + quad) ^ (l16 & 7)) * 8;
                kf[nt][ks] = *(const bf16x8*)(krow + csw);
                vf[nt][ks] = *(const bf16x8*)(vrow + csw);
            }
        }

        // S^T = K @ Q^T: lane holds key = kt*64+nt*16+quad*4+rr, q = l16
        f32x4 sc[4];
#pragma unroll
        for (int nt = 0; nt < 4; nt++) {
            f32x4 ss = (f32x4){0.f, 0.f, 0.f, 0.f};
            ss = __builtin_amdgcn_mfma_f32_16x16x32_bf16(kf[nt][0], aQ[0], ss, 0, 0, 0);
            ss = __builtin_amdgcn_mfma_f32_16x16x32_bf16(kf[nt][1], aQ[1], ss, 0, 0, 0);
            sc[nt] = ss;
        }
        if (kt == qt) {  // causal mask on the diagonal tile
            int qg = qt * 64 + wave * 16 + l16;
#pragma unroll
            for (int nt = 0; nt < 4; nt++)
#pragma unroll
                for (int rr = 0; rr < 4; rr++)
                    if (kt * 64 + nt * 16 + quad * 4 + rr > qg) sc[nt][rr] = -1e30f;
        }
        L += exp_pwrite(sc, Ps, wave, quad, l16);

        // O += P @ V (per-wave Ps slab; LDS in-order within wave -> no barrier)
#pragma unroll
        for (int ks = 0; ks < 2; ks++) {
            int csw = ((ks * 4 + quad) ^ (l16 & 7)) * 8;
            bf16x8 aP = *(const bf16x8*)(Ps + (wave * 16 + l16) * 64 + csw);
#pragma unroll
            for (int nt = 0; nt < 4; nt++)
                O[nt] = __builtin_amdgcn_mfma_f32_16x16x32_bf16(aP, vf[nt][ks],
                                                                O[nt], 0, 0, 0);
        }
        __syncthreads();  // all waves done with cur + next buffer staged
    }

    float il[4];
#pragma unroll
    for (int rr = 0; rr < 4; rr++) il[rr] = 1.f / __shfl(L, quad * 4 + rr);
#pragma unroll
    for (int nt = 0; nt < 4; nt++) {
#pragma unroll
        for (int rr = 0; rr < 4; rr++) {
            int qoff = wave * 16 + quad * 4 + rr;
            int col = h * 64 + nt * 16 + l16;
            ctx[(size_t)(b * 2048 + qt * 64 + qoff) * 1024 + col] =
                (bf16_t)(O[nt][rr] * il[rr]);
        }
    }
}

// ---------------- out projection: 64x128 tiles, 512 blocks ----------------
__global__ __launch_bounds__(256) void out_gemm(
    const bf16_t* __restrict__ A, const bf16_t* __restrict__ BT,
    const float* __restrict__ bias, float* __restrict__ Cout) {
    const int KD = 1024;
    __shared__ bf16_t As[2][64 * 32];
    __shared__ bf16_t Bs[2][128 * 32];
    int tid = threadIdx.x;
    int wave = tid >> 6, lane = tid & 63;
    int quad = lane >> 4, l16 = lane & 15;
    int wm = wave >> 1, wn = wave & 1;   // waves: 2 (m) x 2 (n)
    int m0 = blockIdx.x * 64;
    int n0 = blockIdx.y * 128;

    int r = tid >> 2;
    int c8 = (((tid & 3) ^ ((tid >> 3) & 3))) * 8;
    const bf16_t* gA  = A + (size_t)(m0 + r) * KD + c8;
    const bf16_t* gB0 = BT + (size_t)(n0 + r) * KD + c8;
    const bf16_t* gB1 = BT + (size_t)(n0 + 64 + r) * KD + c8;

    f32x4 acc[2][4];
#pragma unroll
    for (int i = 0; i < 2; i++)
#pragma unroll
        for (int j = 0; j < 4; j++) acc[i][j] = (f32x4){0.f, 0.f, 0.f, 0.f};

    async_load16(gA, As[0] + wave * 512);
    async_load16(gB0, Bs[0] + wave * 512);
    async_load16(gB1, Bs[0] + 2048 + wave * 512);
    __syncthreads();

    for (int kk = 0; kk < 32; kk++) {
        int cur = kk & 1;
        if (kk < 31) {
            int k0 = (kk + 1) * 32;
            async_load16(gA + k0, As[cur ^ 1] + wave * 512);
            async_load16(gB0 + k0, Bs[cur ^ 1] + wave * 512);
            async_load16(gB1 + k0, Bs[cur ^ 1] + 2048 + wave * 512);
        }
        bf16x8 af[2], bfr[4];
        int csw = (quad ^ ((l16 >> 1) & 3)) * 8;
#pragma unroll
        for (int mt = 0; mt < 2; mt++)
            af[mt] = *(const bf16x8*)(As[cur] + (wm * 32 + mt * 16 + l16) * 32 + csw);
#pragma unroll
        for (int nt = 0; nt < 4; nt++)
            bfr[nt] = *(const bf16x8*)(Bs[cur] + (wn * 64 + nt * 16 + l16) * 32 + csw);
#pragma unroll
        for (int mt = 0; mt < 2; mt++)
#pragma unroll
            for (int nt = 0; nt < 4; nt++)
                acc[mt][nt] = __builtin_amdgcn_mfma_f32_16x16x32_bf16(af[mt], bfr[nt],
                                                                      acc[mt][nt], 0, 0, 0);
        __syncthreads();
    }

#pragma unroll
    for (int mt = 0; mt < 2; mt++) {
        int mg_base = m0 + wm * 32 + mt * 16 + quad * 4;
#pragma unroll
        for (int nt = 0; nt < 4; nt++) {
            int ng = n0 + wn * 64 + nt * 16 + l16;
            float bv = bias[ng];
#pragma unroll
            for (int rr = 0; rr < 4; rr++) {
                int mg = mg_base + rr;
                Cout[(size_t)mg * 1024 + ng] = acc[mt][nt][rr] + bv;
            }
        }
    }
}

extern "C" void kernel_launch(void* const* d_in, const int* in_sizes, int n_in,
                              void* d_out, int out_size, void* d_ws, size_t ws_size,
                              hipStream_t stream) {
    const float* x  = (const float*)d_in[0];
    const float* Wq = (const float*)d_in[1];
    const float* Wk = (const float*)d_in[2];
    const float* Wv = (const float*)d_in[3];
    const float* Wo = (const float*)d_in[4];
    const float* bo = (const float*)d_in[5];
    float* out = (float*)d_out;
    char* ws = (char*)d_ws;

    bf16_t* xb   = (bf16_t*)(ws);                       // 8 MB
    bf16_t* WTs  = (bf16_t*)(ws + (8u << 20));          // 4x2 MB
    bf16_t* WqT  = WTs;
    bf16_t* WkT  = WTs + 1048576;
    bf16_t* WvT  = WTs + 2097152;
    bf16_t* WoT  = WTs + 3145728;
    bf16_t* Qb   = (bf16_t*)(ws + (16u << 20));         // 8 MB natural
    bf16_t* Kb   = (bf16_t*)(ws + (24u << 20));         // 8 MB tiled-swizzled
    bf16_t* Vb   = (bf16_t*)(ws + (32u << 20));         // 8 MB tiled-swizzled V^T
    bf16_t* ctxb = (bf16_t*)(ws + (40u << 20));         // 8 MB

    cvt_f32_bf16<<<4096, 256, 0, stream>>>(x, xb, (4096 * 1024) / 4);
    transpose_cvt4<<<dim3(16, 16, 4), 256, 0, stream>>>(Wq, Wk, Wv, Wo, WTs);
    qkv_gemm<<<dim3(32, 8, 3), 256, 0, stream>>>(xb, WqT, WkT, WvT, Qb, Kb, Vb);
    attn<<<dim3(32, 32), 256, 0, stream>>>(Qb, Kb, Vb, ctxb);
    out_gemm<<<dim3(64, 8), 256, 0, stream>>>(ctxb, WoT, bo, out);
}

// Round 6
// 186.586 us; speedup vs baseline: 1.2201x; 1.1693x over previous
//
#include <hip/hip_runtime.h>
#include <hip/hip_bf16.h>

// Round 6: register-staged pipelined GEMMs.
// - qkv_gemm/out_gemm: buffer_load -> VGPR stage -> ds_write, with raw
//   "s_waitcnt lgkmcnt(0); s_barrier" (NO vmcnt drain). Compiler emits only
//   dependency-driven vmcnt(N) before each ds_write -> tile k+2 loads stay in
//   flight across barriers (the AITER pattern __syncthreads can't express).
// - attn / cvt / transpose unchanged from round 5.

typedef __bf16 bf16_t;
typedef __bf16 bf16x4 __attribute__((ext_vector_type(4)));
typedef __bf16 bf16x8 __attribute__((ext_vector_type(8)));
typedef float f32x4 __attribute__((ext_vector_type(4)));

#define AS_GLOBAL __attribute__((address_space(1)))
#define AS_LDS    __attribute__((address_space(3)))

__device__ __forceinline__ void async_load16(const void* g, void* l) {
    __builtin_amdgcn_global_load_lds((AS_GLOBAL void*)(g), (AS_LDS void*)(l), 16, 0, 0);
}

// Barrier that drains LDS ops only -- leaves global loads in flight.
__device__ __forceinline__ void barrier_lgkm() {
    asm volatile("s_waitcnt lgkmcnt(0)\n\ts_barrier" ::: "memory");
}

// ---------------- fp32 -> bf16 conversion (x) ----------------
__global__ __launch_bounds__(256) void cvt_f32_bf16(const float* __restrict__ src,
                                                    bf16_t* __restrict__ dst, int n4) {
    int i = blockIdx.x * 256 + threadIdx.x;
    if (i < n4) {
        float4 v = ((const float4*)src)[i];
        bf16x4 o;
        o[0] = (bf16_t)v.x; o[1] = (bf16_t)v.y; o[2] = (bf16_t)v.z; o[3] = (bf16_t)v.w;
        ((bf16x4*)dst)[i] = o;
    }
}

// ---------------- 4x fp32 [K,N] -> bf16 transposed [N,K], fused ----------------
__global__ __launch_bounds__(256) void transpose_cvt4(
    const float* __restrict__ W0, const float* __restrict__ W1,
    const float* __restrict__ W2, const float* __restrict__ W3,
    bf16_t* __restrict__ outbase) {
    __shared__ bf16_t T[64][65];
    int t = threadIdx.x;
    int k0 = blockIdx.x * 64, n0 = blockIdx.y * 64, z = blockIdx.z;
    const float* W = (z == 0) ? W0 : (z == 1) ? W1 : (z == 2) ? W2 : W3;
    bf16_t* WT = outbase + (size_t)z * 1048576;
#pragma unroll
    for (int c = 0; c < 4; c++) {
        int idx = c * 256 + t;
        int row = idx >> 4;
        int col4 = (idx & 15) * 4;
        float4 v = *(const float4*)(W + (k0 + row) * 1024 + n0 + col4);
        T[row][col4 + 0] = (bf16_t)v.x;
        T[row][col4 + 1] = (bf16_t)v.y;
        T[row][col4 + 2] = (bf16_t)v.z;
        T[row][col4 + 3] = (bf16_t)v.w;
    }
    __syncthreads();
#pragma unroll
    for (int c = 0; c < 4; c++) {
        int idx = c * 256 + t;
        int nrow = idx >> 4;
        int kc4 = (idx & 15) * 4;
        bf16x4 o;
        o[0] = T[kc4 + 0][nrow];
        o[1] = T[kc4 + 1][nrow];
        o[2] = T[kc4 + 2][nrow];
        o[3] = T[kc4 + 3][nrow];
        *(bf16x4*)(WT + (n0 + nrow) * 1024 + k0 + kc4) = o;
    }
}

// ---------------- fused QKV GEMM (register-staged pipeline) ----------------
// z=0: Q natural [B,H,S,64]
// z=1: K tiled-swizzled: per (b,h): [kt][row=s%64][chunk^(row%8)][d%8]
// z=2: V^T tiled-swizzled: per (b,h): [kt][d][chunk^(d%8)][s%8]
__global__ __launch_bounds__(256) void qkv_gemm(
    const bf16_t* __restrict__ A,
    const bf16_t* __restrict__ WqT, const bf16_t* __restrict__ WkT,
    const bf16_t* __restrict__ WvT,
    bf16_t* __restrict__ Qo, bf16_t* __restrict__ Ko, bf16_t* __restrict__ Vo) {
    const int KD = 1024;
    __shared__ __align__(16) bf16_t As[2][4096];
    __shared__ __align__(16) bf16_t Bs[2][4096];
    int tid = threadIdx.x;
    int wave = tid >> 6, lane = tid & 63;
    int quad = lane >> 4, l16 = lane & 15;
    int wm = wave >> 1, wn = wave & 1;
    int z = blockIdx.z;
    const bf16_t* BT = (z == 0) ? WqT : (z == 1) ? WkT : WvT;
    int m0 = blockIdx.x * 128;
    int n0 = blockIdx.y * 128;

    int r = tid >> 2;
    int c8 = (((tid & 3) ^ ((tid >> 3) & 3))) * 8;  // staged chunk swizzle
    const bf16_t* gA0 = A + (size_t)(m0 + r) * KD + c8;
    const bf16_t* gA1 = A + (size_t)(m0 + 64 + r) * KD + c8;
    const bf16_t* gB0 = BT + (size_t)(n0 + r) * KD + c8;
    const bf16_t* gB1 = BT + (size_t)(n0 + 64 + r) * KD + c8;

    f32x4 acc[4][4];
#pragma unroll
    for (int i = 0; i < 4; i++)
#pragma unroll
        for (int j = 0; j < 4; j++) acc[i][j] = (f32x4){0.f, 0.f, 0.f, 0.f};

    // prologue: tile 0 straight to LDS buf0; tile 1 into stage regs
    int4 sa0 = *(const int4*)gA0, sa1 = *(const int4*)gA1;
    int4 sb0 = *(const int4*)gB0, sb1 = *(const int4*)gB1;
    *(int4*)(As[0] + tid * 8) = sa0;
    *(int4*)(As[0] + 2048 + tid * 8) = sa1;
    *(int4*)(Bs[0] + tid * 8) = sb0;
    *(int4*)(Bs[0] + 2048 + tid * 8) = sb1;
    sa0 = *(const int4*)(gA0 + 32); sa1 = *(const int4*)(gA1 + 32);
    sb0 = *(const int4*)(gB0 + 32); sb1 = *(const int4*)(gB1 + 32);

    int csw = (quad ^ ((l16 >> 1) & 3)) * 8;
#pragma unroll 1
    for (int kk = 0; kk < 32; kk += 2) {
        // ---- even phase: compute tile kk from buf0; stage kk+1 -> buf1; load kk+2
        barrier_lgkm();
        bf16x8 af[4], bfr[4];
#pragma unroll
        for (int mt = 0; mt < 4; mt++)
            af[mt] = *(const bf16x8*)(As[0] + (wm * 64 + mt * 16 + l16) * 32 + csw);
#pragma unroll
        for (int nt = 0; nt < 4; nt++)
            bfr[nt] = *(const bf16x8*)(Bs[0] + (wn * 64 + nt * 16 + l16) * 32 + csw);
        *(int4*)(As[1] + tid * 8) = sa0;
        *(int4*)(As[1] + 2048 + tid * 8) = sa1;
        *(int4*)(Bs[1] + tid * 8) = sb0;
        *(int4*)(Bs[1] + 2048 + tid * 8) = sb1;
        if (kk + 2 < 32) {
            int k0 = (kk + 2) * 32;
            sa0 = *(const int4*)(gA0 + k0); sa1 = *(const int4*)(gA1 + k0);
            sb0 = *(const int4*)(gB0 + k0); sb1 = *(const int4*)(gB1 + k0);
        }
        if (z == 2) {
#pragma unroll
            for (int mt = 0; mt < 4; mt++)
#pragma unroll
                for (int nt = 0; nt < 4; nt++)
                    acc[mt][nt] = __builtin_amdgcn_mfma_f32_16x16x32_bf16(
                        bfr[nt], af[mt], acc[mt][nt], 0, 0, 0);
        } else {
#pragma unroll
            for (int mt = 0; mt < 4; mt++)
#pragma unroll
                for (int nt = 0; nt < 4; nt++)
                    acc[mt][nt] = __builtin_amdgcn_mfma_f32_16x16x32_bf16(
                        af[mt], bfr[nt], acc[mt][nt], 0, 0, 0);
        }
        // ---- odd phase: compute tile kk+1 from buf1; stage kk+2 -> buf0; load kk+3
        barrier_lgkm();
#pragma unroll
        for (int mt = 0; mt < 4; mt++)
            af[mt] = *(const bf16x8*)(As[1] + (wm * 64 + mt * 16 + l16) * 32 + csw);
#pragma unroll
        for (int nt = 0; nt < 4; nt++)
            bfr[nt] = *(const bf16x8*)(Bs[1] + (wn * 64 + nt * 16 + l16) * 32 + csw);
        if (kk + 2 < 32) {
            *(int4*)(As[0] + tid * 8) = sa0;
            *(int4*)(As[0] + 2048 + tid * 8) = sa1;
            *(int4*)(Bs[0] + tid * 8) = sb0;
            *(int4*)(Bs[0] + 2048 + tid * 8) = sb1;
            if (kk + 3 < 32) {
                int k0 = (kk + 3) * 32;
                sa0 = *(const int4*)(gA0 + k0); sa1 = *(const int4*)(gA1 + k0);
                sb0 = *(const int4*)(gB0 + k0); sb1 = *(const int4*)(gB1 + k0);
            }
        }
        if (z == 2) {
#pragma unroll
            for (int mt = 0; mt < 4; mt++)
#pragma unroll
                for (int nt = 0; nt < 4; nt++)
                    acc[mt][nt] = __builtin_amdgcn_mfma_f32_16x16x32_bf16(
                        bfr[nt], af[mt], acc[mt][nt], 0, 0, 0);
        } else {
#pragma unroll
            for (int mt = 0; mt < 4; mt++)
#pragma unroll
                for (int nt = 0; nt < 4; nt++)
                    acc[mt][nt] = __builtin_amdgcn_mfma_f32_16x16x32_bf16(
                        af[mt], bfr[nt], acc[mt][nt], 0, 0, 0);
        }
    }

    if (z == 0) {
#pragma unroll
        for (int mt = 0; mt < 4; mt++) {
            int mg_base = m0 + wm * 64 + mt * 16 + quad * 4;
#pragma unroll
            for (int nt = 0; nt < 4; nt++) {
                int ng = n0 + wn * 64 + nt * 16 + l16;
                int h = ng >> 6, d = ng & 63;
#pragma unroll
                for (int rr = 0; rr < 4; rr++) {
                    int mg = mg_base + rr;
                    int b = mg >> 11, s = mg & 2047;
                    Qo[(((size_t)(b * 16 + h) * 2048) + s) * 64 + d] =
                        (bf16_t)acc[mt][nt][rr];
                }
            }
        }
    } else if (z == 1) {
#pragma unroll
        for (int mt = 0; mt < 4; mt++) {
            int mg_base = m0 + wm * 64 + mt * 16 + quad * 4;
#pragma unroll
            for (int nt = 0; nt < 4; nt++) {
                int ng = n0 + wn * 64 + nt * 16 + l16;
                int h = ng >> 6, dd = ng & 63;
#pragma unroll
                for (int rr = 0; rr < 4; rr++) {
                    int mg = mg_base + rr;
                    int b = mg >> 11, sl = mg & 2047;
                    int kt = sl >> 6, row = sl & 63;
                    int cc = (dd >> 3) ^ (row & 7);
                    Ko[(size_t)(b * 16 + h) * 131072 + kt * 4096 + row * 64 +
                       cc * 8 + (dd & 7)] = (bf16_t)acc[mt][nt][rr];
                }
            }
        }
    } else {
#pragma unroll
        for (int mt = 0; mt < 4; mt++) {
            int sg = m0 + wm * 64 + mt * 16 + l16;
            int b = sg >> 11, sl = sg & 2047;
            int kt = sl >> 6, srow = sl & 63;
#pragma unroll
            for (int nt = 0; nt < 4; nt++) {
                int dg_base = n0 + wn * 64 + nt * 16 + quad * 4;
#pragma unroll
                for (int rr = 0; rr < 4; rr++) {
                    int dg = dg_base + rr;
                    int h = dg >> 6, dd = dg & 63;
                    int cc = (srow >> 3) ^ (dd & 7);
                    Vo[(size_t)(b * 16 + h) * 131072 + kt * 4096 + dd * 64 +
                       cc * 8 + (srow & 7)] = (bf16_t)acc[mt][nt][rr];
                }
            }
        }
    }
}

// ---------------- flash attention (round 5, unchanged) ----------------
__device__ __forceinline__ float exp_pwrite(f32x4 sc[4], bf16_t* Ps,
                                            int wave, int quad, int l16) {
    float part = 0.f;
    int rowbase = (wave * 16 + l16) * 64;
    int gran = (quad & 1) * 4;
    int chi = quad >> 1;
#pragma unroll
    for (int nt = 0; nt < 4; nt++) {
        f32x4 p;
#pragma unroll
        for (int rr = 0; rr < 4; rr++) {
            p[rr] = __builtin_amdgcn_exp2f(sc[nt][rr]);
            part += p[rr];
        }
        bf16x4 pb;
#pragma unroll
        for (int rr = 0; rr < 4; rr++) pb[rr] = (bf16_t)p[rr];
        int cc = (nt * 2 + chi) ^ (l16 & 7);
        *(bf16x4*)(Ps + rowbase + cc * 8 + gran) = pb;
    }
    part += __shfl_xor(part, 16);
    part += __shfl_xor(part, 32);
    return part;
}

__global__ __launch_bounds__(256) void attn(
    const bf16_t* __restrict__ Q, const bf16_t* __restrict__ Kt,
    const bf16_t* __restrict__ Vt, bf16_t* __restrict__ ctx) {
    const int S = 2048;
    __shared__ bf16_t Ks[2][4096];
    __shared__ bf16_t Vs[2][4096];
    __shared__ bf16_t Ps[4096];
    int tid = threadIdx.x, wave = tid >> 6, lane = tid & 63;
    int quad = lane >> 4, l16 = lane & 15;

    int f = blockIdx.x + 32 * blockIdx.y;
    int g = f >> 8, s = f & 255;
    int qt = (g & 1) ? (31 - (s & 31)) : (s & 31);
    int bh = (s >> 5) + 8 * g;
    int h = bh & 15, b = bh >> 4;

    const bf16_t* Qbh = Q + (size_t)bh * S * 64;
    const bf16_t* Kbh = Kt + (size_t)bh * 131072;
    const bf16_t* Vbh = Vt + (size_t)bh * 131072;

    const float qs = 0.125f * 1.44269504f;
    bf16x8 aQ[2];
    {
        const bf16_t* rq = Qbh + (size_t)(qt * 64 + wave * 16 + l16) * 64;
#pragma unroll
        for (int ks = 0; ks < 2; ks++) {
            bf16x8 t = *(const bf16x8*)(rq + ks * 32 + quad * 8);
#pragma unroll
            for (int j = 0; j < 8; j++) t[j] = (bf16_t)((float)t[j] * qs);
            aQ[ks] = t;
        }
    }

    float L = 0.f;
    f32x4 O[4];
#pragma unroll
    for (int i = 0; i < 4; i++) O[i] = (f32x4){0.f, 0.f, 0.f, 0.f};

    {
        const bf16_t* kg = Kbh + tid * 8;
        const bf16_t* vg = Vbh + tid * 8;
        async_load16(kg, Ks[0] + wave * 512);
        async_load16(kg + 2048, Ks[0] + 2048 + wave * 512);
        async_load16(vg, Vs[0] + wave * 512);
        async_load16(vg + 2048, Vs[0] + 2048 + wave * 512);
    }
    __syncthreads();

    for (int kt = 0; kt <= qt; kt++) {
        int cur = kt & 1;
        if (kt < qt) {
            const bf16_t* kg = Kbh + (kt + 1) * 4096 + tid * 8;
            const bf16_t* vg = Vbh + (kt + 1) * 4096 + tid * 8;
            async_load16(kg, Ks[cur ^ 1] + wave * 512);
            async_load16(kg + 2048, Ks[cur ^ 1] + 2048 + wave * 512);
            async_load16(vg, Vs[cur ^ 1] + wave * 512);
            async_load16(vg + 2048, Vs[cur ^ 1] + 2048 + wave * 512);
        }

        bf16x8 kf[4][2], vf[4][2];
#pragma unroll
        for (int nt = 0; nt < 4; nt++) {
            const bf16_t* krow = Ks[cur] + (nt * 16 + l16) * 64;
            const bf16_t* vrow = Vs[cur] + (nt * 16 + l16) * 64;
#pragma unroll
            for (int ks = 0; ks < 2; ks++) {
                int csw = ((ks * 4 + quad) ^ (l16 & 7)) * 8;
                kf[nt][ks] = *(const bf16x8*)(krow + csw);
                vf[nt][ks] = *(const bf16x8*)(vrow + csw);
            }
        }

        f32x4 sc[4];
#pragma unroll
        for (int nt = 0; nt < 4; nt++) {
            f32x4 ss = (f32x4){0.f, 0.f, 0.f, 0.f};
            ss = __builtin_amdgcn_mfma_f32_16x16x32_bf16(kf[nt][0], aQ[0], ss, 0, 0, 0);
            ss = __builtin_amdgcn_mfma_f32_16x16x32_bf16(kf[nt][1], aQ[1], ss, 0, 0, 0);
            sc[nt] = ss;
        }
        if (kt == qt) {
            int qg = qt * 64 + wave * 16 + l16;
#pragma unroll
            for (int nt = 0; nt < 4; nt++)
#pragma unroll
                for (int rr = 0; rr < 4; rr++)
                    if (kt * 64 + nt * 16 + quad * 4 + rr > qg) sc[nt][rr] = -1e30f;
        }
        L += exp_pwrite(sc, Ps, wave, quad, l16);

#pragma unroll
        for (int ks = 0; ks < 2; ks++) {
            int csw = ((ks * 4 + quad) ^ (l16 & 7)) * 8;
            bf16x8 aP = *(const bf16x8*)(Ps + (wave * 16 + l16) * 64 + csw);
#pragma unroll
            for (int nt = 0; nt < 4; nt++)
                O[nt] = __builtin_amdgcn_mfma_f32_16x16x32_bf16(aP, vf[nt][ks],
                                                                O[nt], 0, 0, 0);
        }
        __syncthreads();
    }

    float il[4];
#pragma unroll
    for (int rr = 0; rr < 4; rr++) il[rr] = 1.f / __shfl(L, quad * 4 + rr);
#pragma unroll
    for (int nt = 0; nt < 4; nt++) {
#pragma unroll
        for (int rr = 0; rr < 4; rr++) {
            int qoff = wave * 16 + quad * 4 + rr;
            int col = h * 64 + nt * 16 + l16;
            ctx[(size_t)(b * 2048 + qt * 64 + qoff) * 1024 + col] =
                (bf16_t)(O[nt][rr] * il[rr]);
        }
    }
}

// ---------------- out projection (register-staged pipeline, 64x128) ----------------
__global__ __launch_bounds__(256) void out_gemm(
    const bf16_t* __restrict__ A, const bf16_t* __restrict__ BT,
    const float* __restrict__ bias, float* __restrict__ Cout) {
    const int KD = 1024;
    __shared__ __align__(16) bf16_t As[2][2048];
    __shared__ __align__(16) bf16_t Bs[2][4096];
    int tid = threadIdx.x;
    int wave = tid >> 6, lane = tid & 63;
    int quad = lane >> 4, l16 = lane & 15;
    int wm = wave >> 1, wn = wave & 1;
    int m0 = blockIdx.x * 64;
    int n0 = blockIdx.y * 128;

    int r = tid >> 2;
    int c8 = (((tid & 3) ^ ((tid >> 3) & 3))) * 8;
    const bf16_t* gA  = A + (size_t)(m0 + r) * KD + c8;
    const bf16_t* gB0 = BT + (size_t)(n0 + r) * KD + c8;
    const bf16_t* gB1 = BT + (size_t)(n0 + 64 + r) * KD + c8;

    f32x4 acc[2][4];
#pragma unroll
    for (int i = 0; i < 2; i++)
#pragma unroll
        for (int j = 0; j < 4; j++) acc[i][j] = (f32x4){0.f, 0.f, 0.f, 0.f};

    int4 sa = *(const int4*)gA;
    int4 sb0 = *(const int4*)gB0, sb1 = *(const int4*)gB1;
    *(int4*)(As[0] + tid * 8) = sa;
    *(int4*)(Bs[0] + tid * 8) = sb0;
    *(int4*)(Bs[0] + 2048 + tid * 8) = sb1;
    sa = *(const int4*)(gA + 32);
    sb0 = *(const int4*)(gB0 + 32); sb1 = *(const int4*)(gB1 + 32);

    int csw = (quad ^ ((l16 >> 1) & 3)) * 8;
#pragma unroll 1
    for (int kk = 0; kk < 32; kk += 2) {
        barrier_lgkm();
        bf16x8 af[2], bfr[4];
#pragma unroll
        for (int mt = 0; mt < 2; mt++)
            af[mt] = *(const bf16x8*)(As[0] + (wm * 32 + mt * 16 + l16) * 32 + csw);
#pragma unroll
        for (int nt = 0; nt < 4; nt++)
            bfr[nt] = *(const bf16x8*)(Bs[0] + (wn * 64 + nt * 16 + l16) * 32 + csw);
        *(int4*)(As[1] + tid * 8) = sa;
        *(int4*)(Bs[1] + tid * 8) = sb0;
        *(int4*)(Bs[1] + 2048 + tid * 8) = sb1;
        if (kk + 2 < 32) {
            int k0 = (kk + 2) * 32;
            sa = *(const int4*)(gA + k0);
            sb0 = *(const int4*)(gB0 + k0); sb1 = *(const int4*)(gB1 + k0);
        }
#pragma unroll
        for (int mt = 0; mt < 2; mt++)
#pragma unroll
            for (int nt = 0; nt < 4; nt++)
                acc[mt][nt] = __builtin_amdgcn_mfma_f32_16x16x32_bf16(af[mt], bfr[nt],
                                                                      acc[mt][nt], 0, 0, 0);
        barrier_lgkm();
#pragma unroll
        for (int mt = 0; mt < 2; mt++)
            af[mt] = *(const bf16x8*)(As[1] + (wm * 32 + mt * 16 + l16) * 32 + csw);
#pragma unroll
        for (int nt = 0; nt < 4; nt++)
            bfr[nt] = *(const bf16x8*)(Bs[1] + (wn * 64 + nt * 16 + l16) * 32 + csw);
        if (kk + 2 < 32) {
            *(int4*)(As[0] + tid * 8) = sa;
            *(int4*)(Bs[0] + tid * 8) = sb0;
            *(int4*)(Bs[0] + 2048 + tid * 8) = sb1;
            if (kk + 3 < 32) {
                int k0 = (kk + 3) * 32;
                sa = *(const int4*)(gA + k0);
                sb0 = *(const int4*)(gB0 + k0); sb1 = *(const int4*)(gB1 + k0);
            }
        }
#pragma unroll
        for (int mt = 0; mt < 2; mt++)
#pragma unroll
            for (int nt = 0; nt < 4; nt++)
                acc[mt][nt] = __builtin_amdgcn_mfma_f32_16x16x32_bf16(af[mt], bfr[nt],
                                                                      acc[mt][nt], 0, 0, 0);
    }

#pragma unroll
    for (int mt = 0; mt < 2; mt++) {
        int mg_base = m0 + wm * 32 + mt * 16 + quad * 4;
#pragma unroll
        for (int nt = 0; nt < 4; nt++) {
            int ng = n0 + wn * 64 + nt * 16 + l16;
            float bv = bias[ng];
#pragma unroll
            for (int rr = 0; rr < 4; rr++) {
                int mg = mg_base + rr;
                Cout[(size_t)mg * 1024 + ng] = acc[mt][nt][rr] + bv;
            }
        }
    }
}

extern "C" void kernel_launch(void* const* d_in, const int* in_sizes, int n_in,
                              void* d_out, int out_size, void* d_ws, size_t ws_size,
                              hipStream_t stream) {
    const float* x  = (const float*)d_in[0];
    const float* Wq = (const float*)d_in[1];
    const float* Wk = (const float*)d_in[2];
    const float* Wv = (const float*)d_in[3];
    const float* Wo = (const float*)d_in[4];
    const float* bo = (const float*)d_in[5];
    float* out = (float*)d_out;
    char* ws = (char*)d_ws;

    bf16_t* xb   = (bf16_t*)(ws);                       // 8 MB
    bf16_t* WTs  = (bf16_t*)(ws + (8u << 20));          // 4x2 MB
    bf16_t* WqT  = WTs;
    bf16_t* WkT  = WTs + 1048576;
    bf16_t* WvT  = WTs + 2097152;
    bf16_t* WoT  = WTs + 3145728;
    bf16_t* Qb   = (bf16_t*)(ws + (16u << 20));         // 8 MB natural
    bf16_t* Kb   = (bf16_t*)(ws + (24u << 20));         // 8 MB tiled-swizzled
    bf16_t* Vb   = (bf16_t*)(ws + (32u << 20));         // 8 MB tiled-swizzled V^T
    bf16_t* ctxb = (bf16_t*)(ws + (40u << 20));         // 8 MB

    cvt_f32_bf16<<<4096, 256, 0, stream>>>(x, xb, (4096 * 1024) / 4);
    transpose_cvt4<<<dim3(16, 16, 4), 256, 0, stream>>>(Wq, Wk, Wv, Wo, WTs);
    qkv_gemm<<<dim3(32, 8, 3), 256, 0, stream>>>(xb, WqT, WkT, WvT, Qb, Kb, Vb);
    attn<<<dim3(32, 32), 256, 0, stream>>>(Qb, Kb, Vb, ctxb);
    out_gemm<<<dim3(64, 8), 256, 0, stream>>>(ctxb, WoT, bo, out);
}